// Round 13
// baseline (193.641 us; speedup 1.0000x reference)
//
#include <hip/hip_runtime.h>

// ModulatedConv2d (StyleGAN2): B=8, Cin=Cout=512, k=3, H=W=64.
//   s[b,c]     = style @ (mod_weight/sqrt(512))^T + bias          (fp32)
//   scale[b,o] = cs * rsqrt(cs^2 * sum_c wsq[o,c]*s^2 + eps)
//   out[b,o,p] = scale[b,o] * sum_{c,k} w[o,c,k] * (s[b,c]*x[b,c,p'])
// k_conv v13: 4 WAVES PER SIMD (occupancy attack). Occupancy trend:
// 1/SIMD=35%, 2/SIMD=43-46% across 8 schedule variants -> the MFMA pipe
// needs more independent instruction streams, not better intra-wave
// scheduling. Wave = 32o x 4y x 32x (acc 4 frags, 64 VGPR; total ~120
// < 128 budget), block = 8 waves = 64o x 16y x 32x, grid 512 = 2
// blocks/CU = 16 waves/CU. W direct L2->reg (3 gathers/kx), X double-
// buffered LDS (2 x 24KB), barrier-only phase end (in-order vmcnt via
// A-loads retires stage DMAs mid-phase).

typedef __bf16 bf16x8 __attribute__((ext_vector_type(8)));
typedef float f32x16 __attribute__((ext_vector_type(16)));

#define AS1 __attribute__((address_space(1)))
#define AS3 __attribute__((address_space(3)))
#define SB __builtin_amdgcn_sched_barrier(0)

__device__ __forceinline__ unsigned short f2bf(float f) {
  union { float f; unsigned int u; } v; v.f = f;
  unsigned int u = v.u;
  return (unsigned short)((u + 0x7fffu + ((u >> 16) & 1u)) >> 16);
}

__device__ __forceinline__ float dot8(float4 a0, float4 a1, float4 b0, float4 b1) {
  return a0.x*b0.x + a0.y*b0.y + a0.z*b0.z + a0.w*b0.w +
         a1.x*b1.x + a1.y*b1.y + a1.z*b1.z + a1.w*b1.w;
}

// s[b,c]: one wave per 4 outputs, lanes split d (coalesced 32B/lane).
__global__ __launch_bounds__(256) void k_mod(
    const float* __restrict__ style, const float* __restrict__ mw,
    const float* __restrict__ mb, float* __restrict__ s,
    float* __restrict__ zp) {
  if (blockIdx.x == 0) {                    // 4KB zero page
    zp[threadIdx.x] = 0.f; zp[256 + threadIdx.x] = 0.f;
    zp[512 + threadIdx.x] = 0.f; zp[768 + threadIdx.x] = 0.f;
  }
  int wv = blockIdx.x * 4 + (threadIdx.x >> 6);   // 0..1023
  int lane = threadIdx.x & 63;
  int t0 = wv * 4;
#pragma unroll
  for (int j = 0; j < 4; ++j) {
    int t = t0 + j, b = t >> 9, c = t & 511;
    const float4* mp = (const float4*)(mw + (size_t)c * 512 + lane * 8);
    const float4* sp = (const float4*)(style + (size_t)b * 512 + lane * 8);
    float p = dot8(mp[0], mp[1], sp[0], sp[1]);
#pragma unroll
    for (int off = 32; off; off >>= 1) p += __shfl_xor(p, off);
    if (lane == 0) s[t] = p * 0.04419417382415922f + mb[c];
  }
}

// wbf2[tap][c16(32)][o(512)][16c] bf16 + wsq[o][c]; per thread 2 c's.
__global__ __launch_bounds__(256) void k_wprep(
    const float* __restrict__ w, float* __restrict__ wsq,
    unsigned short* __restrict__ wbf2) {
  __shared__ float wl[4608];
  int o = blockIdx.x;              // 512
  int t = threadIdx.x;             // 256
  const float* wp = w + (size_t)o * 4608;
  for (int i = t; i < 4608; i += 256) wl[i] = wp[i];
  __syncthreads();
  int c0 = t * 2;
  float q0 = 0.f, q1 = 0.f;
  unsigned int rr[9];
#pragma unroll
  for (int k = 0; k < 9; ++k) {
    float v0 = wl[c0 * 9 + k], v1 = wl[c0 * 9 + 9 + k];
    q0 += v0 * v0; q1 += v1 * v1;
    rr[k] = (unsigned int)f2bf(v0) | ((unsigned int)f2bf(v1) << 16);
  }
  *(float2*)&wsq[o * 512 + c0] = make_float2(q0, q1);
#pragma unroll
  for (int k = 0; k < 9; ++k) {
    size_t idx = ((size_t)(k * 32 + (c0 >> 4)) * 512 + o) * 16 + (c0 & 15);
    *(unsigned int*)&wbf2[idx] = rr[k];
  }
}

// scale[b,o]: one wave per o; wsq row read once (coalesced), 8 dots vs s^2.
__global__ __launch_bounds__(256) void k_scale(
    const float* __restrict__ wsq, const float* __restrict__ s,
    float* __restrict__ scale) {
  int o = blockIdx.x * 4 + (threadIdx.x >> 6);    // 128 blocks
  int lane = threadIdx.x & 63;
  const float4* wp = (const float4*)(wsq + (size_t)o * 512 + lane * 8);
  float4 w0 = wp[0], w1 = wp[1];
  const float cs = 0.014731391274719739f;   // 1/sqrt(4608)
#pragma unroll
  for (int b = 0; b < 8; ++b) {
    const float4* sp = (const float4*)(s + (size_t)b * 512 + lane * 8);
    float4 s0 = sp[0], s1 = sp[1];
    s0.x *= s0.x; s0.y *= s0.y; s0.z *= s0.z; s0.w *= s0.w;
    s1.x *= s1.x; s1.y *= s1.y; s1.z *= s1.z; s1.w *= s1.w;
    float p = dot8(w0, w1, s0, s1);
#pragma unroll
    for (int off = 32; off; off >>= 1) p += __shfl_xor(p, off);
    if (lane == 0) scale[b * 512 + o] = cs * rsqrtf(cs * cs * p + 1e-8f);
  }
}

// xt[b][y][x][c] = bf16(s[b,c] * x[b,c,y,x]).
__global__ void k_xt(const float* __restrict__ x, const float* __restrict__ s,
                     unsigned short* __restrict__ xt) {
  __shared__ __align__(16) unsigned short tile[64 * 65 * 8];  // 66560 B
  int bid = blockIdx.x;            // 512 = b(8) * y(64)
  int b = bid >> 6, y = bid & 63;
  int t = threadIdx.x;             // 512
  int co = t >> 3, xo = t & 7;
  const float* xbase = x + ((size_t)(b * 512 + co * 8) * 64 + y) * 64 + xo * 8;
  float4 v[8][2];
#pragma unroll
  for (int j = 0; j < 8; ++j) {
    v[j][0] = *(const float4*)(xbase + (size_t)j * 4096);
    v[j][1] = *(const float4*)(xbase + (size_t)j * 4096 + 4);
  }
  float sv[8];
#pragma unroll
  for (int j = 0; j < 8; ++j) sv[j] = s[b * 512 + co * 8 + j];
#pragma unroll
  for (int k = 0; k < 8; ++k) {
    unsigned short r[8];
#pragma unroll
    for (int j = 0; j < 8; ++j) {
      float f = (k < 4) ? ((const float*)&v[j][0])[k & 3]
                        : ((const float*)&v[j][1])[k & 3];
      r[j] = f2bf(f * sv[j]);
    }
    int xr = xo * 8 + k;
    int unit = xr * 65 + (co ^ xr);
    *(ulonglong2*)&tile[unit * 8] = *(ulonglong2*)r;
  }
  __syncthreads();
  unsigned short* obase = xt + ((size_t)(b * 64 + y) * 64) * 512;
#pragma unroll
  for (int i = 0; i < 8; ++i) {
    int unit_o = i * 512 + t;
    int xr = unit_o >> 6, cor = unit_o & 63;
    int unit = xr * 65 + (cor ^ xr);
    *(ulonglong2*)&obase[(size_t)unit_o * 8] = *(const ulonglong2*)&tile[unit * 8];
  }
}

// ---------------- k_conv v13 ----------------
// Block = 64o x 16y x 32x, 8 waves: wid = wyy(0..3)*2 + wo(0..1).
// Wave = 32o x (4y x 32x), acc = 4 f32x16 frags.
// X LDS buffer (24 issues x 1024B = 24KB; entries e<1224 real, rest pad),
// double-buffered. entry e = chunk(0..1)*612 + row(0..17)*34 + xi(0..33):
//   holds xt[yg*16+row-1][xg*32+xi-1][cc*16 + chunk*8 ..+7] (zp if OOB/pad)
// W: direct global->reg from wbf2[tap][c16][o][16c]; A-frag = coalesced
// 1KB gather (32 o's, both c-halves), 3 per kx.
#define BUFU  12288      // ushorts per buffer (24576 B)

__global__ __launch_bounds__(512, 4) void k_conv(
    const unsigned short* __restrict__ xt, const unsigned short* __restrict__ wbf2,
    const float* __restrict__ scale, const float* __restrict__ zp,
    float* __restrict__ out) {
  __shared__ __align__(16) unsigned short lds[2 * BUFU];  // 49152 B

  int bid = blockIdx.x;            // 512 = 8 b * 8 ob * 4 yg * 2 xg
  int b = bid & 7;                 // XCD k owns batch b=k
  int rest = bid >> 3;
  int ob = rest & 7;
  int rest2 = rest >> 3;
  int yg = rest2 & 3;
  int xg = rest2 >> 2;

  int tid = threadIdx.x;
  int wid = tid >> 6;              // 0..7
  int wo = wid & 1, wyy = wid >> 1;
  int lane = tid & 63, ln31 = lane & 31, hi = lane >> 5;

  // ---- X staging source pointers (3 issues per thread), +32B/phase ----
  const char* srcp[3];
  const char* xglob = (const char*)(xt + (size_t)b * 64 * 64 * 512);
#pragma unroll
  for (int i = 0; i < 3; ++i) {
    int is = wid + i * 8;          // 0..23
    int e = is * 64 + lane;
    int chunk = e / 612;
    int rem = e - chunk * 612;
    int row = rem / 34;
    int xi = rem - row * 34;
    int y = yg * 16 + row - 1, x = xg * 32 + xi - 1;
    bool ok = (chunk < 2) && (y >= 0) && (y < 64) && (x >= 0) && (x < 64);
    srcp[i] = ok ? xglob + 2 * ((y * 64 + x) * 512 + chunk * 8)
                 : (const char*)zp;
  }

  // ---- A (weight) lane base: wbf2[tap][c16][o][16c], o = ob*64+wo*32+ln31 ----
  const char* aw0 = (const char*)wbf2 +
      2 * (((size_t)(ob * 64 + wo * 32 + ln31)) * 16 + hi * 8);

  f32x16 acc[4];   // [ry]
#pragma unroll
  for (int i = 0; i < 4; ++i)
    acc[i] = (f32x16){0,0,0,0,0,0,0,0,0,0,0,0,0,0,0,0};

  auto STAGE = [&](int bufu) {
#pragma unroll
    for (int i = 0; i < 3; ++i) {
      __builtin_amdgcn_global_load_lds(
          (const AS1 void*)srcp[i],
          (AS3 void*)&lds[bufu + (wid + i * 8) * 512], 16, 0, 0);
      srcp[i] += 32;
    }
  };

  const unsigned short* Xw = &lds[(hi * 612 + wyy * 136 + ln31) * 8];

  STAGE(0);                         // phase 0 -> buf0
  asm volatile("s_waitcnt vmcnt(0)" ::: "memory");
  __builtin_amdgcn_s_barrier();
  SB;

#pragma unroll 1
  for (int t = 0; t < 32; ++t) {
    const unsigned short* Xbp = Xw + (t & 1) * BUFU;
    if (t < 31) STAGE(((t + 1) & 1) * BUFU);
    int aoff = t * 16384;
#pragma unroll
    for (int kx = 0; kx < 3; ++kx) {
      bf16x8 bv[6], av[3];
#pragma unroll
      for (int rr = 0; rr < 6; ++rr)
        bv[rr] = *(const bf16x8*)&Xbp[(rr * 34 + kx) * 8];
#pragma unroll
      for (int ky = 0; ky < 3; ++ky)
        av[ky] = *(const bf16x8*)(aw0 + (size_t)(ky * 3 + kx) * 524288 + aoff);
      __builtin_amdgcn_s_setprio(1);
#pragma unroll
      for (int ky = 0; ky < 3; ++ky)
#pragma unroll
        for (int ry = 0; ry < 4; ++ry)
          acc[ry] = __builtin_amdgcn_mfma_f32_32x32x16_bf16(
              av[ky], bv[ry + ky], acc[ry], 0, 0, 0);
      __builtin_amdgcn_s_setprio(0);
    }
    __builtin_amdgcn_s_barrier();
    SB;
  }

  // ---- epilogue: C/D layout col=lane&31, row=(reg&3)+8*(reg>>2)+4*(lane>>5) ----
  const float* scp = scale + b * 512 + ob * 64 + wo * 32;
  float* op = out + ((size_t)(b * 512 + ob * 64 + wo * 32) * 4096) +
              (yg * 16 + wyy * 4) * 64 + xg * 32 + ln31;
#pragma unroll
  for (int ry = 0; ry < 4; ++ry) {
    const f32x16& A = acc[ry];
#pragma unroll
    for (int reg = 0; reg < 16; ++reg) {
      int orow = (reg & 3) + 8 * (reg >> 2) + hi * 4;
      op[(size_t)orow * 4096 + ry * 64] = A[reg] * scp[orow];
    }
  }
}

extern "C" void kernel_launch(void* const* d_in, const int* in_sizes, int n_in,
                              void* d_out, int out_size, void* d_ws, size_t ws_size,
                              hipStream_t stream) {
  const float* x     = (const float*)d_in[0];  // [8,512,64,64]
  const float* style = (const float*)d_in[1];  // [8,512]
  const float* w     = (const float*)d_in[2];  // [1,512,512,3,3]
  const float* mw    = (const float*)d_in[3];  // [512,512]
  const float* mb    = (const float*)d_in[4];  // [512]
  float* out = (float*)d_out;

  char* ws = (char*)d_ws;
  float* zp    = (float*)ws;                       // 4 KB zeros
  float* s     = (float*)(ws + 4096);              // 16 KB
  float* scale = (float*)(ws + 20480);             // 16 KB
  float* wsq   = (float*)(ws + 36864);             // 1 MB
  unsigned short* wbf2 = (unsigned short*)(ws + 1085440);  // 4.72 MB [9][32][512][16]
  unsigned short* xt   = (unsigned short*)(ws + 5804032);  // 33.5 MB [8][64][64][512]

  k_mod  <<<256,  256, 0, stream>>>(style, mw, mb, s, zp);
  k_wprep<<<512,  256, 0, stream>>>(w, wsq, wbf2);
  k_scale<<<128,  256, 0, stream>>>(wsq, s, scale);
  k_xt   <<<512,  512, 0, stream>>>(x, s, xt);
  k_conv <<<512,  512, 0, stream>>>(xt, wbf2, scale, zp, out);
}

// Round 14
// 180.819 us; speedup vs baseline: 1.0709x; 1.0709x over previous
//
#include <hip/hip_runtime.h>

// ModulatedConv2d (StyleGAN2): B=8, Cin=Cout=512, k=3, H=W=64.
//   s[b,c]     = style @ (mod_weight/sqrt(512))^T + bias          (fp32)
//   scale[b,o] = cs * rsqrt(cs^2 * sum_c wsq[o,c]*s^2 + eps)
//   out[b,o,p] = scale[b,o] * sum_{c,k} w[o,c,k] * (s[b,c]*x[b,c,p'])
// k_conv v14 = v5 data layout + faithful m201 8-phase-style sync:
// per c16-tile, 3 kx-phases {12 ds_read | stage | bar | lgkmcnt(0) |
// setprio | 24 MFMA | setprio | bar}; staging pipelined 2 tiles deep
// (X triple-buf 3x24KB) / 1 deep (W double-buf 2x36KB, 144KB LDS);
// per-tile counted vmcnt(3) (W-before-X stream order), NEVER drained
// mid-loop. Only vmem = stage DMAs (W via LDS again -> clean vmcnt).

typedef __bf16 bf16x8 __attribute__((ext_vector_type(8)));
typedef float f32x16 __attribute__((ext_vector_type(16)));

#define AS1 __attribute__((address_space(1)))
#define AS3 __attribute__((address_space(3)))
#define SB __builtin_amdgcn_sched_barrier(0)

__device__ __forceinline__ unsigned short f2bf(float f) {
  union { float f; unsigned int u; } v; v.f = f;
  unsigned int u = v.u;
  return (unsigned short)((u + 0x7fffu + ((u >> 16) & 1u)) >> 16);
}

__device__ __forceinline__ float dot8(float4 a0, float4 a1, float4 b0, float4 b1) {
  return a0.x*b0.x + a0.y*b0.y + a0.z*b0.z + a0.w*b0.w +
         a1.x*b1.x + a1.y*b1.y + a1.z*b1.z + a1.w*b1.w;
}

// s[b,c]: one wave per 4 outputs, lanes split d (coalesced 32B/lane).
__global__ __launch_bounds__(256) void k_mod(
    const float* __restrict__ style, const float* __restrict__ mw,
    const float* __restrict__ mb, float* __restrict__ s,
    float* __restrict__ zp) {
  if (blockIdx.x == 0) {                    // 4KB zero page
    zp[threadIdx.x] = 0.f; zp[256 + threadIdx.x] = 0.f;
    zp[512 + threadIdx.x] = 0.f; zp[768 + threadIdx.x] = 0.f;
  }
  int wv = blockIdx.x * 4 + (threadIdx.x >> 6);   // 0..1023
  int lane = threadIdx.x & 63;
  int t0 = wv * 4;
#pragma unroll
  for (int j = 0; j < 4; ++j) {
    int t = t0 + j, b = t >> 9, c = t & 511;
    const float4* mp = (const float4*)(mw + (size_t)c * 512 + lane * 8);
    const float4* sp = (const float4*)(style + (size_t)b * 512 + lane * 8);
    float p = dot8(mp[0], mp[1], sp[0], sp[1]);
#pragma unroll
    for (int off = 32; off; off >>= 1) p += __shfl_xor(p, off);
    if (lane == 0) s[t] = p * 0.04419417382415922f + mb[c];
  }
}

// wbf[k][o][c] bf16 + wsq[o][c]; per thread 2 c's; coalesced writes.
__global__ __launch_bounds__(256) void k_wprep(
    const float* __restrict__ w, float* __restrict__ wsq,
    unsigned short* __restrict__ wbf) {
  __shared__ float wl[4608];
  int o = blockIdx.x;              // 512
  int t = threadIdx.x;             // 256
  const float* wp = w + (size_t)o * 4608;
  for (int i = t; i < 4608; i += 256) wl[i] = wp[i];
  __syncthreads();
  int c0 = t * 2;
  float q0 = 0.f, q1 = 0.f;
  unsigned int rr[9];
#pragma unroll
  for (int k = 0; k < 9; ++k) {
    float v0 = wl[c0 * 9 + k], v1 = wl[c0 * 9 + 9 + k];
    q0 += v0 * v0; q1 += v1 * v1;
    rr[k] = (unsigned int)f2bf(v0) | ((unsigned int)f2bf(v1) << 16);
  }
  *(float2*)&wsq[o * 512 + c0] = make_float2(q0, q1);
#pragma unroll
  for (int k = 0; k < 9; ++k)
    *(unsigned int*)&wbf[((size_t)k * 512 + o) * 512 + c0] = rr[k];
}

// scale[b,o]: one wave per o; wsq row read once (coalesced), 8 dots vs s^2.
__global__ __launch_bounds__(256) void k_scale(
    const float* __restrict__ wsq, const float* __restrict__ s,
    float* __restrict__ scale) {
  int o = blockIdx.x * 4 + (threadIdx.x >> 6);    // 128 blocks
  int lane = threadIdx.x & 63;
  const float4* wp = (const float4*)(wsq + (size_t)o * 512 + lane * 8);
  float4 w0 = wp[0], w1 = wp[1];
  const float cs = 0.014731391274719739f;   // 1/sqrt(4608)
#pragma unroll
  for (int b = 0; b < 8; ++b) {
    const float4* sp = (const float4*)(s + (size_t)b * 512 + lane * 8);
    float4 s0 = sp[0], s1 = sp[1];
    s0.x *= s0.x; s0.y *= s0.y; s0.z *= s0.z; s0.w *= s0.w;
    s1.x *= s1.x; s1.y *= s1.y; s1.z *= s1.z; s1.w *= s1.w;
    float p = dot8(w0, w1, s0, s1);
#pragma unroll
    for (int off = 32; off; off >>= 1) p += __shfl_xor(p, off);
    if (lane == 0) scale[b * 512 + o] = cs * rsqrtf(cs * cs * p + 1e-8f);
  }
}

// xt[b][y][x][c] = bf16(s[b,c] * x[b,c,y,x]).
__global__ void k_xt(const float* __restrict__ x, const float* __restrict__ s,
                     unsigned short* __restrict__ xt) {
  __shared__ __align__(16) unsigned short tile[64 * 65 * 8];  // 66560 B
  int bid = blockIdx.x;            // 512 = b(8) * y(64)
  int b = bid >> 6, y = bid & 63;
  int t = threadIdx.x;             // 512
  int co = t >> 3, xo = t & 7;
  const float* xbase = x + ((size_t)(b * 512 + co * 8) * 64 + y) * 64 + xo * 8;
  float4 v[8][2];
#pragma unroll
  for (int j = 0; j < 8; ++j) {
    v[j][0] = *(const float4*)(xbase + (size_t)j * 4096);
    v[j][1] = *(const float4*)(xbase + (size_t)j * 4096 + 4);
  }
  float sv[8];
#pragma unroll
  for (int j = 0; j < 8; ++j) sv[j] = s[b * 512 + co * 8 + j];
#pragma unroll
  for (int k = 0; k < 8; ++k) {
    unsigned short r[8];
#pragma unroll
    for (int j = 0; j < 8; ++j) {
      float f = (k < 4) ? ((const float*)&v[j][0])[k & 3]
                        : ((const float*)&v[j][1])[k & 3];
      r[j] = f2bf(f * sv[j]);
    }
    int xr = xo * 8 + k;
    int unit = xr * 65 + (co ^ xr);
    *(ulonglong2*)&tile[unit * 8] = *(ulonglong2*)r;
  }
  __syncthreads();
  unsigned short* obase = xt + ((size_t)(b * 64 + y) * 64) * 512;
#pragma unroll
  for (int i = 0; i < 8; ++i) {
    int unit_o = i * 512 + t;
    int xr = unit_o >> 6, cor = unit_o & 63;
    int unit = xr * 65 + (cor ^ xr);
    *(ulonglong2*)&obase[(size_t)unit_o * 8] = *(const ulonglong2*)&tile[unit * 8];
  }
}

// ---------------- k_conv v14 ----------------
// Block = 128o x 16y x 32x, 8 waves: wid = wyy(0..3)*2 + wo(0..1).
// Wave = 64o x (4y x 32x), acc = 8 f32x16 frags.
// LDS (ushort idx): X buffers @ 0 / 12288 / 24576 (24 issues x 1KB each);
//                   W buffers @ 36864 / 55296   (36 issues x 1KB each).
// X entry e = chunk(0..1)*612 + row(0..17)*34 + xi(0..33):
//   xt[yg*16+row-1][xg*32+xi-1][cc*16+chunk*8 ..+7]  (zp if OOB/pad)
// W entry e2 = chunk*1152 + tap*128 + o(0..127): wbf[tap][ob*128+o][cc*16+..]
// Pipeline: tile t stages W(t+1) (phases 0-1) then X(t+2) (phase 2);
// per-thread stream = [5 W][3 X] -> vmcnt(3) at tile end retires W(t+1)
// and X(t+1), leaves X(t+2) in flight. No mid-loop drain.
#define XS0 0
#define XS1 12288
#define XS2 24576
#define WS0 36864
#define WS1 55296

__global__ __launch_bounds__(512, 2) void k_conv(
    const unsigned short* __restrict__ xt, const unsigned short* __restrict__ wbf,
    const float* __restrict__ scale, const float* __restrict__ zp,
    float* __restrict__ out) {
  __shared__ __align__(16) unsigned short lds[73728];  // 147456 B

  int bid = blockIdx.x;            // 256 = 8 b * 4 ob * 4 yg * 2 xg
  int b = bid & 7;                 // XCD k owns batch b=k
  int rest = bid >> 3;
  int ob = rest & 3;
  int rest2 = rest >> 2;
  int yg = rest2 & 3;
  int xg = rest2 >> 2;

  int tid = threadIdx.x;
  int wid = tid >> 6;              // 0..7
  int wo = wid & 1, wyy = wid >> 1;
  int lane = tid & 63, ln31 = lane & 31, hi = lane >> 5;

  // ---- staging source pointers: 5 W slots + 3 X slots per thread ----
  const char* wsrc[5];
  const char* xsrc[3];
  const char* xglob = (const char*)(xt + (size_t)b * 64 * 64 * 512);
#pragma unroll
  for (int j = 0; j < 5; ++j) {
    int is2 = wid + 24 + j * 8;    // 24..63; real W issues are 24..59
    if (is2 < 60) {
      int e2 = (is2 - 24) * 64 + lane;
      int chunk = e2 / 1152;
      int rem = e2 - chunk * 1152;
      int tap = rem >> 7, o = rem & 127;
      wsrc[j] = (const char*)wbf +
                2 * ((tap * 512 + ob * 128 + o) * 512 + chunk * 8);
    } else {
      wsrc[j] = (const char*)zp;
    }
  }
#pragma unroll
  for (int j = 0; j < 3; ++j) {
    int is = wid + j * 8;          // 0..23
    int e = is * 64 + lane;
    int chunk = e / 612;
    int rem = e - chunk * 612;
    int row = rem / 34;
    int xi = rem - row * 34;
    int y = yg * 16 + row - 1, x = xg * 32 + xi - 1;
    bool ok = (chunk < 2) && (y >= 0) && (y < 64) && (x >= 0) && (x < 64);
    xsrc[j] = ok ? xglob + 2 * ((y * 64 + x) * 512 + chunk * 8)
                 : (const char*)zp;
  }

  f32x16 acc[8];   // [oh*4 + ry]
#pragma unroll
  for (int i = 0; i < 8; ++i)
    acc[i] = (f32x16){0,0,0,0,0,0,0,0,0,0,0,0,0,0,0,0};

  auto stageW = [&](int j, int wsb) {
    int is2 = wid + 24 + j * 8;
    if (is2 < 60) {
      __builtin_amdgcn_global_load_lds(
          (const AS1 void*)wsrc[j],
          (AS3 void*)&lds[wsb + (is2 - 24) * 512], 16, 0, 0);
      wsrc[j] += 32;
    }
  };
  auto stageX = [&](int j, int xsb) {
    __builtin_amdgcn_global_load_lds(
        (const AS1 void*)xsrc[j],
        (AS3 void*)&lds[xsb + (wid + j * 8) * 512], 16, 0, 0);
    xsrc[j] += 32;
  };

  // One kx-phase: {12 ds_read | stage | bar | lgkm(0) | prio MFMA prio | bar}
  // sk: 0 -> stage W slots 0-2; 1 -> W slots 3-4; 2 -> X slots 0-2.
  // wait: 0 none, 1 vmcnt(3), 2 vmcnt(0)  (before closing barrier).
  auto PHASE = [&](const unsigned short* Xr, const unsigned short* Wr, int kx,
                   int sk, int sbase, bool sg, int wait) {
    bf16x8 bv[6], av[6];
#pragma unroll
    for (int rr = 0; rr < 6; ++rr)
      bv[rr] = *(const bf16x8*)&Xr[(rr * 34 + kx) * 8];
#pragma unroll
    for (int ky = 0; ky < 3; ++ky) {
      av[ky * 2]     = *(const bf16x8*)&Wr[(ky * 3 + kx) * 1024];
      av[ky * 2 + 1] = *(const bf16x8*)&Wr[(ky * 3 + kx) * 1024 + 256];
    }
    if (sg) {
      if (sk == 0) { stageW(0, sbase); stageW(1, sbase); stageW(2, sbase); }
      if (sk == 1) { stageW(3, sbase); stageW(4, sbase); }
      if (sk == 2) { stageX(0, sbase); stageX(1, sbase); stageX(2, sbase); }
    }
    SB;
    __builtin_amdgcn_s_barrier();
    asm volatile("s_waitcnt lgkmcnt(0)" ::: "memory");
    SB;
    __builtin_amdgcn_s_setprio(1);
#pragma unroll
    for (int ky = 0; ky < 3; ++ky) {
#pragma unroll
      for (int ry = 0; ry < 4; ++ry) {
        acc[ry] = __builtin_amdgcn_mfma_f32_32x32x16_bf16(
            av[ky * 2], bv[ry + ky], acc[ry], 0, 0, 0);
        acc[4 + ry] = __builtin_amdgcn_mfma_f32_32x32x16_bf16(
            av[ky * 2 + 1], bv[ry + ky], acc[4 + ry], 0, 0, 0);
      }
    }
    __builtin_amdgcn_s_setprio(0);
    SB;
    if (wait == 1) asm volatile("s_waitcnt vmcnt(3)" ::: "memory");
    if (wait == 2) asm volatile("s_waitcnt vmcnt(0)" ::: "memory");
    __builtin_amdgcn_s_barrier();
    SB;
  };

  // One c16-tile = 3 kx-phases; stages W(t+1) in ph0-1, X(t+2) in ph2.
  auto TILE = [&](const unsigned short* Xr, const unsigned short* Wr,
                  int wsb, int xsb, bool sgW, bool sgX, int wcode) {
    PHASE(Xr, Wr, 0, 0, wsb, sgW, 0);
    PHASE(Xr, Wr, 1, 1, wsb, sgW, 0);
    PHASE(Xr, Wr, 2, 2, xsb, sgX, wcode);
  };

  int xoff = (hi * 612 + wyy * 136 + ln31) * 8;
  int woff = (hi * 1152 + wo * 64 + ln31) * 8;
  const unsigned short* Xr0 = &lds[XS0 + xoff];
  const unsigned short* Xr1 = &lds[XS1 + xoff];
  const unsigned short* Xr2 = &lds[XS2 + xoff];
  const unsigned short* Wr0 = &lds[WS0 + woff];
  const unsigned short* Wr1 = &lds[WS1 + woff];

  // Prologue: W(0) -> WS0, X(0) -> XS0, X(1) -> XS1; stream [W5][X3][X3].
#pragma unroll
  for (int j = 0; j < 5; ++j) stageW(j, WS0);
#pragma unroll
  for (int j = 0; j < 3; ++j) stageX(j, XS0);
#pragma unroll
  for (int j = 0; j < 3; ++j) stageX(j, XS1);
  asm volatile("s_waitcnt vmcnt(3)" ::: "memory");
  __builtin_amdgcn_s_barrier();
  SB;

  // Main: 32 tiles; X read t%3 / stage (t+2)%3, W read t%2 / stage (t+1)%2.
#pragma unroll 1
  for (int tt = 0; tt < 30; tt += 6) {
    TILE(Xr0, Wr0, WS1, XS2, true, true, 1);   // t = tt+0
    TILE(Xr1, Wr1, WS0, XS0, true, true, 1);   // t = tt+1
    TILE(Xr2, Wr0, WS1, XS1, true, true, 1);   // t = tt+2
    TILE(Xr0, Wr1, WS0, XS2, true, true, 1);   // t = tt+3
    TILE(Xr1, Wr0, WS1, XS0, true, true, 1);   // t = tt+4
    TILE(Xr2, Wr1, WS0, XS1, true, true, 1);   // t = tt+5
  }
  TILE(Xr0, Wr0, WS1, XS2, true, false, 2);    // t = 30 (stage W31; drain)
  TILE(Xr1, Wr1, WS0, XS0, false, false, 0);   // t = 31

  // ---- epilogue: C/D layout col=lane&31, row=(reg&3)+8*(reg>>2)+4*(lane>>5) ----
  const float* scp = scale + b * 512 + ob * 128 + wo * 64;
  float* op = out + (((size_t)(b * 512 + ob * 128 + wo * 64) * 64) +
                     yg * 16 + wyy * 4) * 64 + xg * 32 + ln31;
#pragma unroll
  for (int oh = 0; oh < 2; ++oh) {
#pragma unroll
    for (int ry = 0; ry < 4; ++ry) {
      const f32x16& A = acc[oh * 4 + ry];
#pragma unroll
      for (int reg = 0; reg < 16; ++reg) {
        int orow = (reg & 3) + 8 * (reg >> 2) + hi * 4;
        int ol = oh * 32 + orow;
        op[(size_t)ol * 4096 + ry * 64] = A[reg] * scp[ol];
      }
    }
  }
}

extern "C" void kernel_launch(void* const* d_in, const int* in_sizes, int n_in,
                              void* d_out, int out_size, void* d_ws, size_t ws_size,
                              hipStream_t stream) {
  const float* x     = (const float*)d_in[0];  // [8,512,64,64]
  const float* style = (const float*)d_in[1];  // [8,512]
  const float* w     = (const float*)d_in[2];  // [1,512,512,3,3]
  const float* mw    = (const float*)d_in[3];  // [512,512]
  const float* mb    = (const float*)d_in[4];  // [512]
  float* out = (float*)d_out;

  char* ws = (char*)d_ws;
  float* zp    = (float*)ws;                       // 4 KB zeros
  float* s     = (float*)(ws + 4096);              // 16 KB
  float* scale = (float*)(ws + 20480);             // 16 KB
  float* wsq   = (float*)(ws + 36864);             // 1 MB
  unsigned short* wbf = (unsigned short*)(ws + 1085440);   // 4.72 MB [9][512][512]
  unsigned short* xt  = (unsigned short*)(ws + 5804032);   // 33.5 MB [8][64][64][512]

  k_mod  <<<256,  256, 0, stream>>>(style, mw, mb, s, zp);
  k_wprep<<<512,  256, 0, stream>>>(w, wsq, wbf);
  k_scale<<<128,  256, 0, stream>>>(wsq, s, scale);
  k_xt   <<<512,  512, 0, stream>>>(x, s, xt);
  k_conv <<<256,  512, 0, stream>>>(xt, wbf, scale, zp, out);
}

// Round 15
// 176.262 us; speedup vs baseline: 1.0986x; 1.0259x over previous
//
#include <hip/hip_runtime.h>

// ModulatedConv2d (StyleGAN2): B=8, Cin=Cout=512, k=3, H=W=64.
//   s[b,c]     = style @ (mod_weight/sqrt(512))^T + bias          (fp32)
//   scale[b,o] = cs * rsqrt(cs^2 * sum_c wsq[o,c]*s^2 + eps)
//   out[b,o,p] = scale[b,o] * sum_{c,k} w[o,c,k] * (s[b,c]*x[b,c,p'])
// v15 = v14's k_conv (best measured: 150.5us, MfmaUtil 47.2%) UNCHANGED
// + prep consolidated 4 kernels -> 2 fused multi-role launches:
//   K1 = k_prep1: blocks 0-511 wprep | 512-767 mod (+zero page)
//   K2 = k_prep2: blocks 0-511 xt    | 512-575 scale
// cutting launch gaps and filling small-kernel tails.

typedef __bf16 bf16x8 __attribute__((ext_vector_type(8)));
typedef float f32x16 __attribute__((ext_vector_type(16)));

#define AS1 __attribute__((address_space(1)))
#define AS3 __attribute__((address_space(3)))
#define SB __builtin_amdgcn_sched_barrier(0)

__device__ __forceinline__ unsigned short f2bf(float f) {
  union { float f; unsigned int u; } v; v.f = f;
  unsigned int u = v.u;
  return (unsigned short)((u + 0x7fffu + ((u >> 16) & 1u)) >> 16);
}

__device__ __forceinline__ float dot8(float4 a0, float4 a1, float4 b0, float4 b1) {
  return a0.x*b0.x + a0.y*b0.y + a0.z*b0.z + a0.w*b0.w +
         a1.x*b1.x + a1.y*b1.y + a1.z*b1.z + a1.w*b1.w;
}

// ---------------- K1: wprep (blocks 0..511) | mod (blocks 512..767) ----------------
// wprep: wbf[k][o][c] bf16 + wsq[o][c]; per thread 2 c's; coalesced writes.
// mod:   s[b,c] = style @ (mw/sqrt(512))^T + mb; one wave per 4 outputs.
__global__ __launch_bounds__(256) void k_prep1(
    const float* __restrict__ w, const float* __restrict__ style,
    const float* __restrict__ mw, const float* __restrict__ mb,
    float* __restrict__ wsq, unsigned short* __restrict__ wbf,
    float* __restrict__ s, float* __restrict__ zp) {
  int blk = blockIdx.x;
  int t = threadIdx.x;
  if (blk < 512) {
    __shared__ float wl[4608];
    int o = blk;
    const float* wp = w + (size_t)o * 4608;
    for (int i = t; i < 4608; i += 256) wl[i] = wp[i];
    __syncthreads();
    int c0 = t * 2;
    float q0 = 0.f, q1 = 0.f;
    unsigned int rr[9];
#pragma unroll
    for (int k = 0; k < 9; ++k) {
      float v0 = wl[c0 * 9 + k], v1 = wl[c0 * 9 + 9 + k];
      q0 += v0 * v0; q1 += v1 * v1;
      rr[k] = (unsigned int)f2bf(v0) | ((unsigned int)f2bf(v1) << 16);
    }
    *(float2*)&wsq[o * 512 + c0] = make_float2(q0, q1);
#pragma unroll
    for (int k = 0; k < 9; ++k)
      *(unsigned int*)&wbf[((size_t)k * 512 + o) * 512 + c0] = rr[k];
  } else {
    int mblk = blk - 512;
    if (mblk == 0) {                    // 4KB zero page
      zp[t] = 0.f; zp[256 + t] = 0.f; zp[512 + t] = 0.f; zp[768 + t] = 0.f;
    }
    int wv = mblk * 4 + (t >> 6);       // 0..1023
    int lane = t & 63;
    int t0 = wv * 4;
#pragma unroll
    for (int j = 0; j < 4; ++j) {
      int tt = t0 + j, b = tt >> 9, c = tt & 511;
      const float4* mp = (const float4*)(mw + (size_t)c * 512 + lane * 8);
      const float4* sp = (const float4*)(style + (size_t)b * 512 + lane * 8);
      float p = dot8(mp[0], mp[1], sp[0], sp[1]);
#pragma unroll
      for (int off = 32; off; off >>= 1) p += __shfl_xor(p, off);
      if (lane == 0) s[tt] = p * 0.04419417382415922f + mb[c];
    }
  }
}

// ---------------- K2: xt (blocks 0..511) | scale (blocks 512..575) ----------------
// xt: xt[b][y][x][c] = bf16(s[b,c]*x[b,c,y,x]); LDS-transposed coalesced.
// scale: one wave per o; wsq row once (coalesced), 8 dots vs s^2.
__global__ __launch_bounds__(512) void k_prep2(
    const float* __restrict__ x, const float* __restrict__ s,
    const float* __restrict__ wsq, unsigned short* __restrict__ xt,
    float* __restrict__ scale) {
  int blk = blockIdx.x;
  int t = threadIdx.x;
  if (blk < 512) {
    __shared__ __align__(16) unsigned short tile[64 * 65 * 8];  // 66560 B
    int b = blk >> 6, y = blk & 63;
    int co = t >> 3, xo = t & 7;
    const float* xbase = x + ((size_t)(b * 512 + co * 8) * 64 + y) * 64 + xo * 8;
    float4 v[8][2];
#pragma unroll
    for (int j = 0; j < 8; ++j) {
      v[j][0] = *(const float4*)(xbase + (size_t)j * 4096);
      v[j][1] = *(const float4*)(xbase + (size_t)j * 4096 + 4);
    }
    float sv[8];
#pragma unroll
    for (int j = 0; j < 8; ++j) sv[j] = s[b * 512 + co * 8 + j];
#pragma unroll
    for (int k = 0; k < 8; ++k) {
      unsigned short r[8];
#pragma unroll
      for (int j = 0; j < 8; ++j) {
        float f = (k < 4) ? ((const float*)&v[j][0])[k & 3]
                          : ((const float*)&v[j][1])[k & 3];
        r[j] = f2bf(f * sv[j]);
      }
      int xr = xo * 8 + k;
      int unit = xr * 65 + (co ^ xr);
      *(ulonglong2*)&tile[unit * 8] = *(ulonglong2*)r;
    }
    __syncthreads();
    unsigned short* obase = xt + ((size_t)(b * 64 + y) * 64) * 512;
#pragma unroll
    for (int i = 0; i < 8; ++i) {
      int unit_o = i * 512 + t;
      int xr = unit_o >> 6, cor = unit_o & 63;
      int unit = xr * 65 + (cor ^ xr);
      *(ulonglong2*)&obase[(size_t)unit_o * 8] = *(const ulonglong2*)&tile[unit * 8];
    }
  } else {
    int o = (blk - 512) * 8 + (t >> 6);     // 64 blocks x 8 waves -> o 0..511
    int lane = t & 63;
    const float4* wp = (const float4*)(wsq + (size_t)o * 512 + lane * 8);
    float4 w0 = wp[0], w1 = wp[1];
    const float cs = 0.014731391274719739f;   // 1/sqrt(4608)
#pragma unroll
    for (int b = 0; b < 8; ++b) {
      const float4* sp = (const float4*)(s + (size_t)b * 512 + lane * 8);
      float4 s0 = sp[0], s1 = sp[1];
      s0.x *= s0.x; s0.y *= s0.y; s0.z *= s0.z; s0.w *= s0.w;
      s1.x *= s1.x; s1.y *= s1.y; s1.z *= s1.z; s1.w *= s1.w;
      float p = dot8(w0, w1, s0, s1);
#pragma unroll
      for (int off = 32; off; off >>= 1) p += __shfl_xor(p, off);
      if (lane == 0) scale[b * 512 + o] = cs * rsqrtf(cs * cs * p + 1e-8f);
    }
  }
}

// ---------------- k_conv (v14, unchanged) ----------------
// Block = 128o x 16y x 32x, 8 waves: wid = wyy(0..3)*2 + wo(0..1).
// Wave = 64o x (4y x 32x), acc = 8 f32x16 frags.
// LDS (ushort idx): X buffers @ 0 / 12288 / 24576 (24 issues x 1KB each);
//                   W buffers @ 36864 / 55296   (36 issues x 1KB each).
// X entry e = chunk(0..1)*612 + row(0..17)*34 + xi(0..33):
//   xt[yg*16+row-1][xg*32+xi-1][cc*16+chunk*8 ..+7]  (zp if OOB/pad)
// W entry e2 = chunk*1152 + tap*128 + o(0..127): wbf[tap][ob*128+o][cc*16+..]
// Pipeline: tile t stages W(t+1) (phases 0-1) then X(t+2) (phase 2);
// per-thread stream = [5 W][3 X] -> vmcnt(3) at tile end retires W(t+1)
// and X(t+1), leaves X(t+2) in flight. No mid-loop drain.
#define XS0 0
#define XS1 12288
#define XS2 24576
#define WS0 36864
#define WS1 55296

__global__ __launch_bounds__(512, 2) void k_conv(
    const unsigned short* __restrict__ xt, const unsigned short* __restrict__ wbf,
    const float* __restrict__ scale, const float* __restrict__ zp,
    float* __restrict__ out) {
  __shared__ __align__(16) unsigned short lds[73728];  // 147456 B

  int bid = blockIdx.x;            // 256 = 8 b * 4 ob * 4 yg * 2 xg
  int b = bid & 7;                 // XCD k owns batch b=k
  int rest = bid >> 3;
  int ob = rest & 3;
  int rest2 = rest >> 2;
  int yg = rest2 & 3;
  int xg = rest2 >> 2;

  int tid = threadIdx.x;
  int wid = tid >> 6;              // 0..7
  int wo = wid & 1, wyy = wid >> 1;
  int lane = tid & 63, ln31 = lane & 31, hi = lane >> 5;

  // ---- staging source pointers: 5 W slots + 3 X slots per thread ----
  const char* wsrc[5];
  const char* xsrc[3];
  const char* xglob = (const char*)(xt + (size_t)b * 64 * 64 * 512);
#pragma unroll
  for (int j = 0; j < 5; ++j) {
    int is2 = wid + 24 + j * 8;    // 24..63; real W issues are 24..59
    if (is2 < 60) {
      int e2 = (is2 - 24) * 64 + lane;
      int chunk = e2 / 1152;
      int rem = e2 - chunk * 1152;
      int tap = rem >> 7, o = rem & 127;
      wsrc[j] = (const char*)wbf +
                2 * ((tap * 512 + ob * 128 + o) * 512 + chunk * 8);
    } else {
      wsrc[j] = (const char*)zp;
    }
  }
#pragma unroll
  for (int j = 0; j < 3; ++j) {
    int is = wid + j * 8;          // 0..23
    int e = is * 64 + lane;
    int chunk = e / 612;
    int rem = e - chunk * 612;
    int row = rem / 34;
    int xi = rem - row * 34;
    int y = yg * 16 + row - 1, x = xg * 32 + xi - 1;
    bool ok = (chunk < 2) && (y >= 0) && (y < 64) && (x >= 0) && (x < 64);
    xsrc[j] = ok ? xglob + 2 * ((y * 64 + x) * 512 + chunk * 8)
                 : (const char*)zp;
  }

  f32x16 acc[8];   // [oh*4 + ry]
#pragma unroll
  for (int i = 0; i < 8; ++i)
    acc[i] = (f32x16){0,0,0,0,0,0,0,0,0,0,0,0,0,0,0,0};

  auto stageW = [&](int j, int wsb) {
    int is2 = wid + 24 + j * 8;
    if (is2 < 60) {
      __builtin_amdgcn_global_load_lds(
          (const AS1 void*)wsrc[j],
          (AS3 void*)&lds[wsb + (is2 - 24) * 512], 16, 0, 0);
      wsrc[j] += 32;
    }
  };
  auto stageX = [&](int j, int xsb) {
    __builtin_amdgcn_global_load_lds(
        (const AS1 void*)xsrc[j],
        (AS3 void*)&lds[xsb + (wid + j * 8) * 512], 16, 0, 0);
    xsrc[j] += 32;
  };

  // One kx-phase: {12 ds_read | stage | bar | lgkm(0) | prio MFMA prio | bar}
  auto PHASE = [&](const unsigned short* Xr, const unsigned short* Wr, int kx,
                   int sk, int sbase, bool sg, int wait) {
    bf16x8 bv[6], av[6];
#pragma unroll
    for (int rr = 0; rr < 6; ++rr)
      bv[rr] = *(const bf16x8*)&Xr[(rr * 34 + kx) * 8];
#pragma unroll
    for (int ky = 0; ky < 3; ++ky) {
      av[ky * 2]     = *(const bf16x8*)&Wr[(ky * 3 + kx) * 1024];
      av[ky * 2 + 1] = *(const bf16x8*)&Wr[(ky * 3 + kx) * 1024 + 256];
    }
    if (sg) {
      if (sk == 0) { stageW(0, sbase); stageW(1, sbase); stageW(2, sbase); }
      if (sk == 1) { stageW(3, sbase); stageW(4, sbase); }
      if (sk == 2) { stageX(0, sbase); stageX(1, sbase); stageX(2, sbase); }
    }
    SB;
    __builtin_amdgcn_s_barrier();
    asm volatile("s_waitcnt lgkmcnt(0)" ::: "memory");
    SB;
    __builtin_amdgcn_s_setprio(1);
#pragma unroll
    for (int ky = 0; ky < 3; ++ky) {
#pragma unroll
      for (int ry = 0; ry < 4; ++ry) {
        acc[ry] = __builtin_amdgcn_mfma_f32_32x32x16_bf16(
            av[ky * 2], bv[ry + ky], acc[ry], 0, 0, 0);
        acc[4 + ry] = __builtin_amdgcn_mfma_f32_32x32x16_bf16(
            av[ky * 2 + 1], bv[ry + ky], acc[4 + ry], 0, 0, 0);
      }
    }
    __builtin_amdgcn_s_setprio(0);
    SB;
    if (wait == 1) asm volatile("s_waitcnt vmcnt(3)" ::: "memory");
    if (wait == 2) asm volatile("s_waitcnt vmcnt(0)" ::: "memory");
    __builtin_amdgcn_s_barrier();
    SB;
  };

  auto TILE = [&](const unsigned short* Xr, const unsigned short* Wr,
                  int wsb, int xsb, bool sgW, bool sgX, int wcode) {
    PHASE(Xr, Wr, 0, 0, wsb, sgW, 0);
    PHASE(Xr, Wr, 1, 1, wsb, sgW, 0);
    PHASE(Xr, Wr, 2, 2, xsb, sgX, wcode);
  };

  int xoff = (hi * 612 + wyy * 136 + ln31) * 8;
  int woff = (hi * 1152 + wo * 64 + ln31) * 8;
  const unsigned short* Xr0 = &lds[XS0 + xoff];
  const unsigned short* Xr1 = &lds[XS1 + xoff];
  const unsigned short* Xr2 = &lds[XS2 + xoff];
  const unsigned short* Wr0 = &lds[WS0 + woff];
  const unsigned short* Wr1 = &lds[WS1 + woff];

  // Prologue: W(0) -> WS0, X(0) -> XS0, X(1) -> XS1; stream [W5][X3][X3].
#pragma unroll
  for (int j = 0; j < 5; ++j) stageW(j, WS0);
#pragma unroll
  for (int j = 0; j < 3; ++j) stageX(j, XS0);
#pragma unroll
  for (int j = 0; j < 3; ++j) stageX(j, XS1);
  asm volatile("s_waitcnt vmcnt(3)" ::: "memory");
  __builtin_amdgcn_s_barrier();
  SB;

  // Main: 32 tiles; X read t%3 / stage (t+2)%3, W read t%2 / stage (t+1)%2.
#pragma unroll 1
  for (int tt = 0; tt < 30; tt += 6) {
    TILE(Xr0, Wr0, WS1, XS2, true, true, 1);   // t = tt+0
    TILE(Xr1, Wr1, WS0, XS0, true, true, 1);   // t = tt+1
    TILE(Xr2, Wr0, WS1, XS1, true, true, 1);   // t = tt+2
    TILE(Xr0, Wr1, WS0, XS2, true, true, 1);   // t = tt+3
    TILE(Xr1, Wr0, WS1, XS0, true, true, 1);   // t = tt+4
    TILE(Xr2, Wr1, WS0, XS1, true, true, 1);   // t = tt+5
  }
  TILE(Xr0, Wr0, WS1, XS2, true, false, 2);    // t = 30 (stage W31; drain)
  TILE(Xr1, Wr1, WS0, XS0, false, false, 0);   // t = 31

  // ---- epilogue: C/D layout col=lane&31, row=(reg&3)+8*(reg>>2)+4*(lane>>5) ----
  const float* scp = scale + b * 512 + ob * 128 + wo * 64;
  float* op = out + (((size_t)(b * 512 + ob * 128 + wo * 64) * 64) +
                     yg * 16 + wyy * 4) * 64 + xg * 32 + ln31;
#pragma unroll
  for (int oh = 0; oh < 2; ++oh) {
#pragma unroll
    for (int ry = 0; ry < 4; ++ry) {
      const f32x16& A = acc[oh * 4 + ry];
#pragma unroll
      for (int reg = 0; reg < 16; ++reg) {
        int orow = (reg & 3) + 8 * (reg >> 2) + hi * 4;
        int ol = oh * 32 + orow;
        op[(size_t)ol * 4096 + ry * 64] = A[reg] * scp[ol];
      }
    }
  }
}

extern "C" void kernel_launch(void* const* d_in, const int* in_sizes, int n_in,
                              void* d_out, int out_size, void* d_ws, size_t ws_size,
                              hipStream_t stream) {
  const float* x     = (const float*)d_in[0];  // [8,512,64,64]
  const float* style = (const float*)d_in[1];  // [8,512]
  const float* w     = (const float*)d_in[2];  // [1,512,512,3,3]
  const float* mw    = (const float*)d_in[3];  // [512,512]
  const float* mb    = (const float*)d_in[4];  // [512]
  float* out = (float*)d_out;

  char* ws = (char*)d_ws;
  float* zp    = (float*)ws;                       // 4 KB zeros
  float* s     = (float*)(ws + 4096);              // 16 KB
  float* scale = (float*)(ws + 20480);             // 16 KB
  float* wsq   = (float*)(ws + 36864);             // 1 MB
  unsigned short* wbf = (unsigned short*)(ws + 1085440);   // 4.72 MB [9][512][512]
  unsigned short* xt  = (unsigned short*)(ws + 5804032);   // 33.5 MB [8][64][64][512]

  k_prep1<<<768, 256, 0, stream>>>(w, style, mw, mb, wsq, wbf, s, zp);
  k_prep2<<<576, 512, 0, stream>>>(x, s, wsq, xt, scale);
  k_conv <<<256, 512, 0, stream>>>(xt, wbf, scale, zp, out);
}